// Round 12
// baseline (137.550 us; speedup 1.0000x reference)
//
#include <hip/hip_runtime.h>
#include <math.h>
#include <float.h>

// Problem constants (from reference)
#define NPT     16384
#define IN_F    34
#define SDIM    4
#define PDIM    22
#define KNN     8
#define WIDTH   126
#define WPAD    128    // padded width for conflict-free LDS
#define NCLS    6
#define ROWS    16     // rows per fused-MLP block (256 threads, 16 lanes/row)

typedef unsigned long long u64;

// ---------------- workspace layout (bytes), total ~4.9 MB ----------------
#define OFF_RANGES 0
#define OFF_S      256
#define OFF_H      (OFF_S    + NPT*SDIM*4)
#define OFF_KIDX   (OFF_H    + NPT*PDIM*4)
#define OFF_KW     (OFF_KIDX + NPT*KNN*4)
#define OFF_XWO1   (OFF_KW   + NPT*KNN*4)

// key = (float_bits(d2) << 32) | j : u64 order == lex (d2, idx) order, which is
// exactly jax.lax.top_k's tie-breaking. d2 >= 0 so float bits are monotone.
#define INITK ((((u64)0x7f7fffffu) << 32) | 0xffffffffu)

__device__ __forceinline__ void ce(u64& a, u64& b) {   // a=min, b=max
    bool lt = a < b;
    u64 mn = lt ? a : b;
    u64 mx = lt ? b : a;
    a = mn; b = mx;
}
__device__ __forceinline__ u64 umin64(u64 a, u64 b) { return a < b ? a : b; }

__device__ __forceinline__ void key_insert(u64 key, u64* u) {
#pragma unroll
    for (int t = 0; t < KNN; ++t) {
        bool lt = key < u[t];
        u64 mn = lt ? key  : u[t];
        u64 mx = lt ? u[t] : key;
        u[t] = mn;
        key  = mx;
    }
}

// match reference numerics: rounded squares, sequential sum, no fma
__device__ __forceinline__ float dist2(const float4 a, const float4 b) {
    float d0 = a.x - b.x;
    float d1 = a.y - b.y;
    float d2 = a.z - b.z;
    float d3 = a.w - b.w;
    return __fadd_rn(__fadd_rn(__fadd_rn(__fmul_rn(d0, d0),
                                         __fmul_rn(d1, d1)),
                               __fmul_rn(d2, d2)),
                     __fmul_rn(d3, d3));
}

// 12-CE bitonic sort of a bitonic 8-sequence (m0..m7), ascending result
#define BITONIC8(m0,m1,m2,m3,m4,m5,m6,m7) \
    ce(m0,m4); ce(m1,m5); ce(m2,m6); ce(m3,m7); \
    ce(m0,m2); ce(m1,m3); ce(m4,m6); ce(m5,m7); \
    ce(m0,m1); ce(m2,m3); ce(m4,m5); ce(m6,m7);

// ---------------------------------------------------------
// s = (x@Ws + bs) + 1000*batch ; h = x@Wh + bh ; XWO1 = x@Wo1 (hoisted out of
// the fused MLP -- it doesn't depend on kNN). 64 slots per row.
__global__ __launch_bounds__(256) void k_sh(const float* __restrict__ x,
                                            const int* __restrict__ batch,
                                            const float* __restrict__ Ws,
                                            const float* __restrict__ bs,
                                            const float* __restrict__ Wh,
                                            const float* __restrict__ bh,
                                            const float* __restrict__ Wo1,
                                            float* __restrict__ S,
                                            float* __restrict__ H,
                                            float* __restrict__ XWO1,
                                            int* __restrict__ ranges) {
    int t = blockIdx.x * blockDim.x + threadIdx.x;
    int i = t >> 6;
    int o = t & 63;
    if (i >= NPT) return;
    if (o == 63) {  // graph ranges from sorted batch
        int b = batch[i];
        if (i == 0 || batch[i - 1] != b) ranges[b * 2]     = i;
        if (i == NPT - 1 || batch[i + 1] != b) ranges[b * 2 + 1] = i + 1;
        return;
    }
    const float* xr = x + (size_t)i * IN_F;
    if (o < SDIM) {
        float acc = 0.f;
        for (int k = 0; k < IN_F; ++k) acc += xr[k] * Ws[k * SDIM + o];
        S[(size_t)i * SDIM + o] = (acc + bs[o]) + 1000.f * (float)batch[i];
    } else if (o < SDIM + PDIM) {
        int p = o - SDIM;
        float acc = 0.f;
        for (int k = 0; k < IN_F; ++k) acc += xr[k] * Wh[k * PDIM + p];
        H[(size_t)i * PDIM + p] = acc + bh[p];
    } else if (o < SDIM + PDIM + IN_F) {
        int p = o - SDIM - PDIM;   // 0..33
        float acc = 0.f;
        for (int k = 0; k < IN_F; ++k) acc += xr[k] * Wo1[k * IN_F + p];
        XWO1[(size_t)i * IN_F + p] = acc;
    }
}

// Fused kNN: 32 lanes per query, interleaved candidates, batch-4 sorting
// networks + butterfly merge of sorted-8 lists (round 7; exact u64 order).
// Round-12: explicit next-batch load prefetch -- the 4 float4s for batch
// bb+1 are issued before batch bb's ~100-instr sort/merge stretch.
__global__ __launch_bounds__(256, 4) void k_knn(const float4* __restrict__ S4,
                                                const int* __restrict__ batch,
                                                const int* __restrict__ ranges,
                                                int* __restrict__ KIDX,
                                                float* __restrict__ KW) {
    const int tid = threadIdx.x;
    const int q   = blockIdx.x * 8 + (tid >> 5);
    const int t   = tid & 31;
    const int b   = batch[q];
    const int gs  = ranges[b * 2];
    const int len = ranges[b * 2 + 1] - gs;
    const float4 sq = S4[q];

    u64 u[KNN];
#pragma unroll
    for (int e = 0; e < KNN; ++e) u[e] = INITK;

    const int nfull = len >> 7;     // full 128-candidate (4/lane) batches
    int j = gs + t;
    float4 s0, s1, s2, s3;
    if (nfull > 0) { s0 = S4[j]; s1 = S4[j + 32]; s2 = S4[j + 64]; s3 = S4[j + 96]; }
    for (int bb = 0; bb < nfull; ++bb) {
        u64 k0 = ((u64)__float_as_uint(dist2(sq, s0)) << 32) | (unsigned)(j);
        u64 k1 = ((u64)__float_as_uint(dist2(sq, s1)) << 32) | (unsigned)(j + 32);
        u64 k2 = ((u64)__float_as_uint(dist2(sq, s2)) << 32) | (unsigned)(j + 64);
        u64 k3 = ((u64)__float_as_uint(dist2(sq, s3)) << 32) | (unsigned)(j + 96);
        j += 128;
        if (bb + 1 < nfull) {   // prefetch next batch; drains under the networks
            s0 = S4[j]; s1 = S4[j + 32]; s2 = S4[j + 64]; s3 = S4[j + 96];
        }
        // sort 4
        ce(k0, k1); ce(k2, k3); ce(k0, k2); ce(k1, k3); ce(k1, k2);
        // half-cleaner vs sorted u, then bitonic cleanup (sequence is bitonic)
        u64 m0 = umin64(k0, u[7]);
        u64 m1 = umin64(k1, u[6]);
        u64 m2 = umin64(k2, u[5]);
        u64 m3 = umin64(k3, u[4]);
        u64 m4 = u[3], m5 = u[2], m6 = u[1], m7 = u[0];
        BITONIC8(m0, m1, m2, m3, m4, m5, m6, m7);
        u[0] = m0; u[1] = m1; u[2] = m2; u[3] = m3;
        u[4] = m4; u[5] = m5; u[6] = m6; u[7] = m7;
    }
    // tail: per-lane <=4 singleton inserts (exact; order irrelevant)
    for (int m = (nfull << 7) + t; m < len; m += 32) {
        int jj = gs + m;
        key_insert(((u64)__float_as_uint(dist2(sq, S4[jj])) << 32) | (unsigned)jj, u);
    }

    // butterfly across the 32-lane group: merge two sorted-8 lists per step
#pragma unroll
    for (int mm = 1; mm < 32; mm <<= 1) {
        u64 p0 = (u64)__shfl_xor((long long)u[0], mm, 32);
        u64 p1 = (u64)__shfl_xor((long long)u[1], mm, 32);
        u64 p2 = (u64)__shfl_xor((long long)u[2], mm, 32);
        u64 p3 = (u64)__shfl_xor((long long)u[3], mm, 32);
        u64 p4 = (u64)__shfl_xor((long long)u[4], mm, 32);
        u64 p5 = (u64)__shfl_xor((long long)u[5], mm, 32);
        u64 p6 = (u64)__shfl_xor((long long)u[6], mm, 32);
        u64 p7 = (u64)__shfl_xor((long long)u[7], mm, 32);
        u64 m0 = umin64(u[0], p7);
        u64 m1 = umin64(u[1], p6);
        u64 m2 = umin64(u[2], p5);
        u64 m3 = umin64(u[3], p4);
        u64 m4 = umin64(u[4], p3);
        u64 m5 = umin64(u[5], p2);
        u64 m6 = umin64(u[6], p1);
        u64 m7 = umin64(u[7], p0);
        BITONIC8(m0, m1, m2, m3, m4, m5, m6, m7);
        u[0] = m0; u[1] = m1; u[2] = m2; u[3] = m3;
        u[4] = m4; u[5] = m5; u[6] = m6; u[7] = m7;
    }

    if (t == 0) {
#pragma unroll
        for (int e = 0; e < KNN; ++e) {
            float d = __uint_as_float((unsigned)(u[e] >> 32));
            KIDX[(size_t)q * KNN + e] = (int)(unsigned)(u[e] & 0xffffffffu);
            KW[(size_t)q * KNN + e]   = expf(-10.f * d);
        }
    }
}

// Fused gather+MLP, round-12:
//  - ROWS=16 @ 256 thr -> grid 1024 = 4 blocks/CU (round-11's grid of 512
//    capped residency at 2 blocks/CU; TLP was the missing latency hider).
//  - W2 via 16-row chunks, LDS double-buffered, loads issued 2 CHUNKS ahead,
//    ONE barrier per chunk.
//  - W1 (17 KB, L1-resident) read direct as float2 -- only W2 busts L1.
//  - x@Wo1 precomputed (XWO1) -> no xt staging, et phase is 44x3 MACs.
//  - LDS 32.6 KB total.
__global__ __launch_bounds__(256, 4) void k_fused(
        const float* __restrict__ XWO1,
        const float* __restrict__ H,
        const int* __restrict__ KIDX,
        const float* __restrict__ KW,
        const float* __restrict__ Wo2,
        const float* __restrict__ bo2,
        const float* __restrict__ W1,
        const float* __restrict__ b1,
        const float* __restrict__ W2,
        const float* __restrict__ b2,
        const float* __restrict__ W3,
        const float* __restrict__ b3,
        float* __restrict__ out) {
    __shared__ float aggt[ROWS * 2 * PDIM];   // 16x44
    __shared__ float et[ROWS * IN_F];         // 16x34
    __shared__ float h1t[ROWS * WPAD];        // 16x128 (cols 126/127 = 0)
    __shared__ float wbuf[2][16 * WPAD];      // W2 pipeline: 2 x 16x128 = 16 KB
    __shared__ float w3buf[WPAD * NCLS];      // 128x6, rows 126/127 = 0
                                              // total = 32640 B -> 4 blocks/CU

    const int tid  = threadIdx.x;
    const int r    = tid >> 4;               // row 0..15
    const int c    = tid & 15;               // lane-in-row 0..15
    const int row0 = blockIdx.x * ROWS;
    const int gi   = row0 + r;
    const int jA   = 4 * c;                  // cols 0..63
    const int jB   = 64 + 4 * c;             // cols 64..127 (126/127 pad)

    float rvA[8], rvB[8];
#define LOADC(RV, K0)                                            \
    _Pragma("unroll")                                            \
    for (int i = 0; i < 8; ++i) {                                \
        int e = i * 256 + tid, kk = e >> 7, j = e & 127;         \
        int row = (K0) + kk;                                     \
        RV[i] = (j < WIDTH && row < WIDTH)                       \
                    ? W2[(size_t)row * WIDTH + j] : 0.f;         \
    }
#define STOREC(BUFI, RV)                                         \
    _Pragma("unroll")                                            \
    for (int i = 0; i < 8; ++i) wbuf[BUFI][i * 256 + tid] = RV[i];

    // issue W2 chunks 0,1 + W3 staging NOW; they drain under gather/et/h1
    LOADC(rvA, 0);
    LOADC(rvB, 16);
    for (int t = tid; t < WPAD * NCLS; t += 256) {
        int k = t / NCLS;
        w3buf[t] = (k < WIDTH) ? W3[t] : 0.f;
    }

    // gather + aggregate: lane c<11 handles dims {c, c+11}
    if (c < 11) {
        const int p0 = c, p1 = c + 11;
        float s0 = 0.f, s1 = 0.f;
        float m0 = -FLT_MAX, m1 = -FLT_MAX;
#pragma unroll
        for (int k = 0; k < KNN; ++k) {
            int   j = KIDX[(size_t)gi * KNN + k];
            float w = KW[(size_t)gi * KNN + k];
            const float* hr = H + (size_t)j * PDIM;
            float v0 = hr[p0] * w; s0 += v0; m0 = fmaxf(m0, v0);
            float v1 = hr[p1] * w; s1 += v1; m1 = fmaxf(m1, v1);
        }
        aggt[r * 44 + p0] = s0 * 0.125f; aggt[r * 44 + PDIM + p0] = m0;
        aggt[r * 44 + p1] = s1 * 0.125f; aggt[r * 44 + PDIM + p1] = m1;
    }
    __syncthreads();   // aggt + w3buf visible

    // et = XWO1 + agg@Wo2 + bo2 ; 3-wide chunks, j0=min(3c,31); overlap lanes
    // write bitwise-identical duplicates (benign)
    {
        const int j0 = (3 * c < 31) ? 3 * c : 31;
        float acc[3] = {0.f, 0.f, 0.f};
        const float* gr = aggt + r * 44;
#pragma unroll 4
        for (int p = 0; p < 2 * PDIM; ++p) {
            float av = gr[p];
            const float* wr = Wo2 + p * IN_F + j0;
#pragma unroll
            for (int jj = 0; jj < 3; ++jj) acc[jj] += av * wr[jj];
        }
        const float* xw = XWO1 + (size_t)gi * IN_F + j0;
#pragma unroll
        for (int jj = 0; jj < 3; ++jj)
            et[r * IN_F + j0 + jj] = xw[jj] + acc[jj] + bo2[j0 + jj];
    }
    __syncthreads();   // et ready

    // h1 = elu(et@W1 + b1), W1 direct from global (L1-resident, float2 loads;
    // W1 rows are 504B-strided so float4 would be misaligned every other row)
    {
        float aA[4] = {0.f, 0.f, 0.f, 0.f};
        float aB[4] = {0.f, 0.f, 0.f, 0.f};
        const float* ar = et + r * IN_F;
        const bool bhi = (jB + 2 < WIDTH);   // lane 15's upper pair is pad
#pragma unroll 2
        for (int k = 0; k < IN_F; ++k) {
            float av = ar[k];
            const float* wr = W1 + k * WIDTH;
            float2 a01 = *(const float2*)(wr + jA);
            float2 a23 = *(const float2*)(wr + jA + 2);
            float2 b01 = *(const float2*)(wr + jB);
            float2 b23 = bhi ? *(const float2*)(wr + jB + 2) : make_float2(0.f, 0.f);
            aA[0] += av * a01.x; aA[1] += av * a01.y;
            aA[2] += av * a23.x; aA[3] += av * a23.y;
            aB[0] += av * b01.x; aB[1] += av * b01.y;
            aB[2] += av * b23.x; aB[3] += av * b23.y;
        }
#pragma unroll
        for (int jj = 0; jj < 4; ++jj) {
            float vA = aA[jj] + b1[jA + jj];
            h1t[r * WPAD + jA + jj] = vA > 0.f ? vA : expm1f(vA);
            int j = jB + jj;
            float vB = aB[jj] + b1[j < WIDTH ? j : WIDTH - 1];
            h1t[r * WPAD + j] = (j < WIDTH) ? (vB > 0.f ? vB : expm1f(vB)) : 0.f;
        }
    }
    __syncthreads();   // h1t ready

    // ---- h2: 8 x 16-row W2 chunks, double-buffered, 1 barrier/chunk ----
    float aA[4] = {0.f, 0.f, 0.f, 0.f};
    float aB[4] = {0.f, 0.f, 0.f, 0.f};
    const float* ar = h1t + r * WPAD;

#define COMPC(BUFI, K0)                                              \
    {                                                                \
        const float* wb = wbuf[BUFI];                                \
        _Pragma("unroll 4")                                          \
        for (int k = 0; k < 16; ++k) {                               \
            float av = ar[(K0) + k];                                 \
            const float4 wA = *(const float4*)(wb + k * WPAD + jA);  \
            const float4 wB = *(const float4*)(wb + k * WPAD + jB);  \
            aA[0] += av * wA.x; aA[1] += av * wA.y;                  \
            aA[2] += av * wA.z; aA[3] += av * wA.w;                  \
            aB[0] += av * wB.x; aB[1] += av * wB.y;                  \
            aB[2] += av * wB.z; aB[3] += av * wB.w;                  \
        }                                                            \
    }

    STOREC(0, rvA); LOADC(rvA, 32);  __syncthreads(); COMPC(0, 0);
    STOREC(1, rvB); LOADC(rvB, 48);  __syncthreads(); COMPC(1, 16);
    STOREC(0, rvA); LOADC(rvA, 64);  __syncthreads(); COMPC(0, 32);
    STOREC(1, rvB); LOADC(rvB, 80);  __syncthreads(); COMPC(1, 48);
    STOREC(0, rvA); LOADC(rvA, 96);  __syncthreads(); COMPC(0, 64);
    STOREC(1, rvB); LOADC(rvB, 112); __syncthreads(); COMPC(1, 80);
    STOREC(0, rvA);                  __syncthreads(); COMPC(0, 96);
    STOREC(1, rvB);                  __syncthreads(); COMPC(1, 112);

    // h2 = elu(acc+b2) in-register; fold out = h2@W3 (w3buf pad rows are 0)
    {
        float pc[NCLS] = {0.f, 0.f, 0.f, 0.f, 0.f, 0.f};
#pragma unroll
        for (int jj = 0; jj < 4; ++jj) {
            int ja = jA + jj;
            float vA = aA[jj] + b2[ja];
            float hA = vA > 0.f ? vA : expm1f(vA);
            const float* w3a = w3buf + ja * NCLS;
#pragma unroll
            for (int cc = 0; cc < NCLS; ++cc) pc[cc] += hA * w3a[cc];
            int jb = jB + jj;
            float vB = aB[jj] + b2[jb < WIDTH ? jb : WIDTH - 1];
            float hB = (jb < WIDTH) ? (vB > 0.f ? vB : expm1f(vB)) : 0.f;
            const float* w3b = w3buf + jb * NCLS;
#pragma unroll
            for (int cc = 0; cc < NCLS; ++cc) pc[cc] += hB * w3b[cc];
        }
#pragma unroll
        for (int mm = 1; mm < 16; mm <<= 1) {
#pragma unroll
            for (int cc = 0; cc < NCLS; ++cc)
                pc[cc] += __shfl_xor(pc[cc], mm, 16);
        }
        if (c == 0) {
#pragma unroll
            for (int cc = 0; cc < NCLS; ++cc)
                out[(size_t)gi * NCLS + cc] = pc[cc] + b3[cc];
        }
    }
#undef LOADC
#undef STOREC
#undef COMPC
}

extern "C" void kernel_launch(void* const* d_in, const int* in_sizes, int n_in,
                              void* d_out, int out_size, void* d_ws, size_t ws_size,
                              hipStream_t stream) {
    const float* x     = (const float*)d_in[0];
    const int*   batch = (const int*)d_in[1];
    // Only conv index NCONV-1 == 1 affects the output (loop discards earlier)
    const float* Ws  = (const float*)d_in[2] + IN_F * SDIM;
    const float* bs  = (const float*)d_in[3] + SDIM;
    const float* Wh  = (const float*)d_in[4] + IN_F * PDIM;
    const float* bh  = (const float*)d_in[5] + PDIM;
    const float* Wo1 = (const float*)d_in[6] + IN_F * IN_F;
    const float* Wo2 = (const float*)d_in[7] + 2 * PDIM * IN_F;
    const float* bo2 = (const float*)d_in[8] + IN_F;
    const float* W1  = (const float*)d_in[9];
    const float* b1  = (const float*)d_in[10];
    const float* W2  = (const float*)d_in[11];
    const float* b2  = (const float*)d_in[12];
    const float* W3  = (const float*)d_in[13];
    const float* b3  = (const float*)d_in[14];
    float* out = (float*)d_out;

    char* ws = (char*)d_ws;
    int*   ranges = (int*)(ws + OFF_RANGES);
    float* S      = (float*)(ws + OFF_S);
    float* H      = (float*)(ws + OFF_H);
    int*   KIDX   = (int*)(ws + OFF_KIDX);
    float* KW     = (float*)(ws + OFF_KW);
    float* XWO1   = (float*)(ws + OFF_XWO1);

    k_sh<<<dim3(NPT * 64 / 256), dim3(256), 0, stream>>>(x, batch, Ws, bs, Wh, bh, Wo1,
                                                         S, H, XWO1, ranges);
    k_knn<<<dim3(NPT / 8), dim3(256), 0, stream>>>((const float4*)S, batch, ranges, KIDX, KW);
    k_fused<<<dim3(NPT / ROWS), dim3(256), 0, stream>>>(XWO1, H, KIDX, KW, Wo2, bo2,
                                                        W1, b1, W2, b2, W3, b3, out);
}

// Round 13
// 93.002 us; speedup vs baseline: 1.4790x; 1.4790x over previous
//
#include <hip/hip_runtime.h>
#include <math.h>
#include <float.h>

// Problem constants (from reference)
#define NPT     16384
#define IN_F    34
#define SDIM    4
#define PDIM    22
#define KNN     8
#define WIDTH   126
#define WPAD    128    // padded width for conflict-free LDS
#define NCLS    6
#define ROWS    32     // rows per fused-MLP block (512 threads, 16 lanes/row)

typedef unsigned long long u64;

// ---------------- workspace layout (bytes), total ~3 MB ----------------
#define OFF_RANGES 0
#define OFF_S      256
#define OFF_H      (OFF_S  + NPT*SDIM*4)
#define OFF_KIDX   (OFF_H  + NPT*PDIM*4)
#define OFF_KW     (OFF_KIDX + NPT*KNN*4)

// key = (float_bits(d2) << 32) | j : u64 order == lex (d2, idx) order, which is
// exactly jax.lax.top_k's tie-breaking. d2 >= 0 so float bits are monotone.
#define INITK ((((u64)0x7f7fffffu) << 32) | 0xffffffffu)

__device__ __forceinline__ void ce(u64& a, u64& b) {   // a=min, b=max
    bool lt = a < b;
    u64 mn = lt ? a : b;
    u64 mx = lt ? b : a;
    a = mn; b = mx;
}
__device__ __forceinline__ u64 umin64(u64 a, u64 b) { return a < b ? a : b; }

__device__ __forceinline__ void key_insert(u64 key, u64* u) {
#pragma unroll
    for (int t = 0; t < KNN; ++t) {
        bool lt = key < u[t];
        u64 mn = lt ? key  : u[t];
        u64 mx = lt ? u[t] : key;
        u[t] = mn;
        key  = mx;
    }
}

// match reference numerics: rounded squares, sequential sum, no fma
__device__ __forceinline__ float dist2(const float4 a, const float4 b) {
    float d0 = a.x - b.x;
    float d1 = a.y - b.y;
    float d2 = a.z - b.z;
    float d3 = a.w - b.w;
    return __fadd_rn(__fadd_rn(__fadd_rn(__fmul_rn(d0, d0),
                                         __fmul_rn(d1, d1)),
                               __fmul_rn(d2, d2)),
                     __fmul_rn(d3, d3));
}

// 12-CE bitonic sort of a bitonic 8-sequence (m0..m7), ascending result
#define BITONIC8(m0,m1,m2,m3,m4,m5,m6,m7) \
    ce(m0,m4); ce(m1,m5); ce(m2,m6); ce(m3,m7); \
    ce(m0,m2); ce(m1,m3); ce(m4,m6); ce(m5,m7); \
    ce(m0,m1); ce(m2,m3); ce(m4,m5); ce(m6,m7);

// Batcher odd-even mergesort network for 8 keys (19 CE), ascending
#define SORT8(k0,k1,k2,k3,k4,k5,k6,k7) \
    ce(k0,k1); ce(k2,k3); ce(k4,k5); ce(k6,k7); \
    ce(k0,k2); ce(k1,k3); ce(k4,k6); ce(k5,k7); \
    ce(k1,k2); ce(k5,k6); \
    ce(k0,k4); ce(k1,k5); ce(k2,k6); ce(k3,k7); \
    ce(k2,k4); ce(k3,k5); \
    ce(k1,k2); ce(k3,k4); ce(k5,k6);

// ---------------------------------------------------------
// s = (x@Ws + bs) + 1000*batch ; h = x@Wh + bh  (conv index 1 weights).
// Thread = (row i, slot o): o<4 -> S, o<26 -> H, o==31 -> graph ranges.
__global__ __launch_bounds__(256) void k_sh(const float* __restrict__ x,
                                            const int* __restrict__ batch,
                                            const float* __restrict__ Ws,
                                            const float* __restrict__ bs,
                                            const float* __restrict__ Wh,
                                            const float* __restrict__ bh,
                                            float* __restrict__ S,
                                            float* __restrict__ H,
                                            int* __restrict__ ranges) {
    int t = blockIdx.x * blockDim.x + threadIdx.x;
    int i = t >> 5;
    int o = t & 31;
    if (i >= NPT) return;
    if (o == 31) {  // graph ranges from sorted batch
        int b = batch[i];
        if (i == 0 || batch[i - 1] != b) ranges[b * 2]     = i;
        if (i == NPT - 1 || batch[i + 1] != b) ranges[b * 2 + 1] = i + 1;
        return;
    }
    const float* xr = x + (size_t)i * IN_F;
    if (o < SDIM) {
        float acc = 0.f;
        for (int k = 0; k < IN_F; ++k) acc += xr[k] * Ws[k * SDIM + o];
        S[(size_t)i * SDIM + o] = (acc + bs[o]) + 1000.f * (float)batch[i];
    } else if (o < SDIM + PDIM) {
        int p = o - SDIM;
        float acc = 0.f;
        for (int k = 0; k < IN_F; ++k) acc += xr[k] * Wh[k * PDIM + p];
        H[(size_t)i * PDIM + p] = acc + bh[p];
    }
}

// Fused kNN: 32 lanes per query, interleaved candidates. Round-13: batch-8
// scan -- Batcher sort-8 (19 CE) + keep-low-8 bitonic merge (8 min + 12 CE)
// per 8 candidates: ~8% fewer network instr than 2x batch-4, half the loop
// overhead, and 8 dwordx4 loads naturally in flight per iteration (the
// latency overlap round-12's branchy prefetch failed to give). Remainder:
// verified batch-4 body, then <=31 singleton inserts. Exact u64 order.
__global__ __launch_bounds__(256, 4) void k_knn(const float4* __restrict__ S4,
                                                const int* __restrict__ batch,
                                                const int* __restrict__ ranges,
                                                int* __restrict__ KIDX,
                                                float* __restrict__ KW) {
    const int tid = threadIdx.x;
    const int q   = blockIdx.x * 8 + (tid >> 5);
    const int t   = tid & 31;
    const int b   = batch[q];
    const int gs  = ranges[b * 2];
    const int len = ranges[b * 2 + 1] - gs;
    const float4 sq = S4[q];

    u64 u[KNN];
#pragma unroll
    for (int e = 0; e < KNN; ++e) u[e] = INITK;

    int j = gs + t;
    int done = 0;

    // full 256-candidate (8/lane) batches
    const int nfull8 = len >> 8;
    for (int bb = 0; bb < nfull8; ++bb, j += 256) {
        const float4* p = S4 + j;
        float4 s0 = p[0];
        float4 s1 = p[32];
        float4 s2 = p[64];
        float4 s3 = p[96];
        float4 s4 = p[128];
        float4 s5 = p[160];
        float4 s6 = p[192];
        float4 s7 = p[224];
        u64 k0 = ((u64)__float_as_uint(dist2(sq, s0)) << 32) | (unsigned)(j);
        u64 k1 = ((u64)__float_as_uint(dist2(sq, s1)) << 32) | (unsigned)(j + 32);
        u64 k2 = ((u64)__float_as_uint(dist2(sq, s2)) << 32) | (unsigned)(j + 64);
        u64 k3 = ((u64)__float_as_uint(dist2(sq, s3)) << 32) | (unsigned)(j + 96);
        u64 k4 = ((u64)__float_as_uint(dist2(sq, s4)) << 32) | (unsigned)(j + 128);
        u64 k5 = ((u64)__float_as_uint(dist2(sq, s5)) << 32) | (unsigned)(j + 160);
        u64 k6 = ((u64)__float_as_uint(dist2(sq, s6)) << 32) | (unsigned)(j + 192);
        u64 k7 = ((u64)__float_as_uint(dist2(sq, s7)) << 32) | (unsigned)(j + 224);
        SORT8(k0, k1, k2, k3, k4, k5, k6, k7);
        // half-cleaner of (ascending k | descending u), keep-low-8 is bitonic
        u64 m0 = umin64(k0, u[7]);
        u64 m1 = umin64(k1, u[6]);
        u64 m2 = umin64(k2, u[5]);
        u64 m3 = umin64(k3, u[4]);
        u64 m4 = umin64(k4, u[3]);
        u64 m5 = umin64(k5, u[2]);
        u64 m6 = umin64(k6, u[1]);
        u64 m7 = umin64(k7, u[0]);
        BITONIC8(m0, m1, m2, m3, m4, m5, m6, m7);
        u[0] = m0; u[1] = m1; u[2] = m2; u[3] = m3;
        u[4] = m4; u[5] = m5; u[6] = m6; u[7] = m7;
    }
    done = nfull8 << 8;

    // at most one 128-candidate (4/lane) batch
    if (len - done >= 128) {
        const float4* p = S4 + j;
        float4 s0 = p[0];
        float4 s1 = p[32];
        float4 s2 = p[64];
        float4 s3 = p[96];
        u64 k0 = ((u64)__float_as_uint(dist2(sq, s0)) << 32) | (unsigned)(j);
        u64 k1 = ((u64)__float_as_uint(dist2(sq, s1)) << 32) | (unsigned)(j + 32);
        u64 k2 = ((u64)__float_as_uint(dist2(sq, s2)) << 32) | (unsigned)(j + 64);
        u64 k3 = ((u64)__float_as_uint(dist2(sq, s3)) << 32) | (unsigned)(j + 96);
        ce(k0, k1); ce(k2, k3); ce(k0, k2); ce(k1, k3); ce(k1, k2);
        u64 m0 = umin64(k0, u[7]);
        u64 m1 = umin64(k1, u[6]);
        u64 m2 = umin64(k2, u[5]);
        u64 m3 = umin64(k3, u[4]);
        u64 m4 = u[3], m5 = u[2], m6 = u[1], m7 = u[0];
        BITONIC8(m0, m1, m2, m3, m4, m5, m6, m7);
        u[0] = m0; u[1] = m1; u[2] = m2; u[3] = m3;
        u[4] = m4; u[5] = m5; u[6] = m6; u[7] = m7;
        done += 128;
    }

    // tail: per-lane <=4 singleton inserts (exact; order irrelevant)
    for (int m = done + t; m < len; m += 32) {
        int jj = gs + m;
        key_insert(((u64)__float_as_uint(dist2(sq, S4[jj])) << 32) | (unsigned)jj, u);
    }

    // butterfly across the 32-lane group: merge two sorted-8 lists per step
#pragma unroll
    for (int mm = 1; mm < 32; mm <<= 1) {
        u64 p0 = (u64)__shfl_xor((long long)u[0], mm, 32);
        u64 p1 = (u64)__shfl_xor((long long)u[1], mm, 32);
        u64 p2 = (u64)__shfl_xor((long long)u[2], mm, 32);
        u64 p3 = (u64)__shfl_xor((long long)u[3], mm, 32);
        u64 p4 = (u64)__shfl_xor((long long)u[4], mm, 32);
        u64 p5 = (u64)__shfl_xor((long long)u[5], mm, 32);
        u64 p6 = (u64)__shfl_xor((long long)u[6], mm, 32);
        u64 p7 = (u64)__shfl_xor((long long)u[7], mm, 32);
        u64 m0 = umin64(u[0], p7);
        u64 m1 = umin64(u[1], p6);
        u64 m2 = umin64(u[2], p5);
        u64 m3 = umin64(u[3], p4);
        u64 m4 = umin64(u[4], p3);
        u64 m5 = umin64(u[5], p2);
        u64 m6 = umin64(u[6], p1);
        u64 m7 = umin64(u[7], p0);
        BITONIC8(m0, m1, m2, m3, m4, m5, m6, m7);
        u[0] = m0; u[1] = m1; u[2] = m2; u[3] = m3;
        u[4] = m4; u[5] = m5; u[6] = m6; u[7] = m7;
    }

    if (t == 0) {
#pragma unroll
        for (int e = 0; e < KNN; ++e) {
            float d = __uint_as_float((unsigned)(u[e] >> 32));
            KIDX[(size_t)q * KNN + e] = (int)(unsigned)(u[e] & 0xffffffffu);
            KW[(size_t)q * KNN + e]   = expf(-10.f * d);
        }
    }
}

// Fused gather+MLP (round-11 version, verbatim -- 97.6us baseline):
//  - ROWS=32 @ 512 threads -> grid 512 = exactly 2 resident blocks/CU.
//  - W2 double-buffered + register-staged: chunk k+1's loads issued before
//    chunk k's compute; ONE barrier per chunk.
//  - chunk0 loads issued before the et phase.
//  - h2 -> out folded in-register (width-16 shfl reduce).
__global__ __launch_bounds__(512, 4) void k_fused(
        const float* __restrict__ x,
        const float* __restrict__ H,
        const int* __restrict__ KIDX,
        const float* __restrict__ KW,
        const float* __restrict__ Wo1,
        const float* __restrict__ Wo2,
        const float* __restrict__ bo2,
        const float* __restrict__ W1,
        const float* __restrict__ b1,
        const float* __restrict__ W2,
        const float* __restrict__ b2,
        const float* __restrict__ W3,
        const float* __restrict__ b3,
        float* __restrict__ out) {
    __shared__ float xt[ROWS * IN_F];       // 32x34
    __shared__ float aggt[ROWS * 2 * PDIM]; // 32x44
    __shared__ float et[ROWS * IN_F];       // 32x34
    __shared__ float h1t[ROWS * WPAD];      // 32x128 (cols 126/127 = 0)
    __shared__ float wbuf[2 * 32 * WPAD];   // 2 x 32x128: W1 (34 rows split
                                            // [0]=rows0-31,[1]=rows32-33), then
                                            // W2 double-buffer. 32 KB.
    __shared__ float w3buf[WPAD * NCLS];    // 128x6, rows 126/127 = 0
                                            // total = 66560 B -> 2 blocks/CU

    const int tid  = threadIdx.x;
    const int r    = tid >> 4;              // row 0..31
    const int c    = tid & 15;              // lane-in-row 0..15
    const int row0 = blockIdx.x * ROWS;
    const int gi   = row0 + r;
    const int jA   = 4 * c;                 // cols 0..63
    const int jB   = 64 + 4 * c;            // cols 64..127 (126/127 pad)

    // ---- staging: x, W1 (rows split over both wbuf halves), W3 ----
    for (int t = tid; t < ROWS * IN_F; t += 512)
        xt[t] = x[(size_t)row0 * IN_F + t];
    for (int t = tid; t < IN_F * WPAD; t += 512) {
        int k = t >> 7, j = t & 127;
        wbuf[(k >> 5) * (32 * WPAD) + (k & 31) * WPAD + j] =
            (j < WIDTH) ? W1[k * WIDTH + j] : 0.f;
    }
    for (int t = tid; t < WPAD * NCLS; t += 512) {
        int k = t / NCLS;
        w3buf[t] = (k < WIDTH) ? W3[t] : 0.f;
    }

    // gather + aggregate: lane c<11 handles dims {c, c+11}
    if (c < 11) {
        const int p0 = c, p1 = c + 11;
        float s0 = 0.f, s1 = 0.f;
        float m0 = -FLT_MAX, m1 = -FLT_MAX;
#pragma unroll
        for (int k = 0; k < KNN; ++k) {
            int   j = KIDX[(size_t)gi * KNN + k];
            float w = KW[(size_t)gi * KNN + k];
            const float* hr = H + (size_t)j * PDIM;
            float v0 = hr[p0] * w; s0 += v0; m0 = fmaxf(m0, v0);
            float v1 = hr[p1] * w; s1 += v1; m1 = fmaxf(m1, v1);
        }
        aggt[r * 44 + p0] = s0 * 0.125f; aggt[r * 44 + PDIM + p0] = m0;
        aggt[r * 44 + p1] = s1 * 0.125f; aggt[r * 44 + PDIM + p1] = m1;
    }
    __syncthreads();   // xt, W1, w3, aggt all visible

    // issue W2 chunk0 loads NOW; they drain under et + h1 compute.
    float rvA[8], rvB[8];
#pragma unroll
    for (int i = 0; i < 8; ++i) {
        int e = i * 512 + tid, kk = e >> 7, j = e & 127;
        rvA[i] = (j < WIDTH) ? W2[(size_t)kk * WIDTH + j] : 0.f;  // rows 0..31
    }

    // et = x@Wo1 + agg@Wo2 + bo2 ; 3-wide chunks, j0=min(3c,31); overlap
    // lanes write bitwise-identical duplicates (benign); Wo1/Wo2 L1/L2-hot
    {
        const int j0 = (3 * c < 31) ? 3 * c : 31;
        float acc[3] = {0.f, 0.f, 0.f};
        const float* ar = xt + r * IN_F;
#pragma unroll 4
        for (int k = 0; k < IN_F; ++k) {
            float av = ar[k];
            const float* wr = Wo1 + k * IN_F + j0;
#pragma unroll
            for (int jj = 0; jj < 3; ++jj) acc[jj] += av * wr[jj];
        }
        const float* gr = aggt + r * 44;
#pragma unroll 4
        for (int p = 0; p < 2 * PDIM; ++p) {
            float av = gr[p];
            const float* wr = Wo2 + p * IN_F + j0;
#pragma unroll
            for (int jj = 0; jj < 3; ++jj) acc[jj] += av * wr[jj];
        }
#pragma unroll
        for (int jj = 0; jj < 3; ++jj)
            et[r * IN_F + j0 + jj] = acc[jj] + bo2[j0 + jj];
    }
    __syncthreads();   // et ready

    // h1 = elu(et@W1 + b1), W1 from LDS (rows k: half k>>5, row k&31)
    {
        float aA[4] = {0.f, 0.f, 0.f, 0.f};
        float aB[4] = {0.f, 0.f, 0.f, 0.f};
        const float* ar = et + r * IN_F;
#pragma unroll 4
        for (int k = 0; k < IN_F; ++k) {
            float av = ar[k];
            const float* wr = wbuf + (k >> 5) * (32 * WPAD) + (k & 31) * WPAD;
            const float4 wA = *(const float4*)(wr + jA);
            const float4 wB = *(const float4*)(wr + jB);
            aA[0] += av * wA.x; aA[1] += av * wA.y;
            aA[2] += av * wA.z; aA[3] += av * wA.w;
            aB[0] += av * wB.x; aB[1] += av * wB.y;
            aB[2] += av * wB.z; aB[3] += av * wB.w;
        }
#pragma unroll
        for (int jj = 0; jj < 4; ++jj) {
            float vA = aA[jj] + b1[jA + jj];
            h1t[r * WPAD + jA + jj] = vA > 0.f ? vA : expm1f(vA);
            int j = jB + jj;
            float vB = aB[jj] + b1[j < WIDTH ? j : WIDTH - 1];
            h1t[r * WPAD + j] = (j < WIDTH) ? (vB > 0.f ? vB : expm1f(vB)) : 0.f;
        }
    }
    __syncthreads();   // h1t ready; ALL W1 reads done -> wbuf reusable

    // ---- h2 with double-buffered W2 (one barrier per chunk) ----
    float aA[4] = {0.f, 0.f, 0.f, 0.f};
    float aB[4] = {0.f, 0.f, 0.f, 0.f};
    const float* ar = h1t + r * WPAD;

#define STORE_CHUNK(BUFI, RV)                                   \
    _Pragma("unroll")                                           \
    for (int i = 0; i < 8; ++i)                                 \
        wbuf[(BUFI) * 4096 + i * 512 + tid] = RV[i];

#define LOAD_CHUNK(RV, K0)                                      \
    _Pragma("unroll")                                           \
    for (int i = 0; i < 8; ++i) {                               \
        int e = i * 512 + tid, kk = e >> 7, j = e & 127;        \
        int row = (K0) + kk;                                    \
        RV[i] = (j < WIDTH && row < WIDTH)                      \
                    ? W2[(size_t)row * WIDTH + j] : 0.f;        \
    }

#define COMPUTE_CHUNK(BUFI, K0)                                 \
    {                                                           \
        const float* wb = wbuf + (BUFI) * 4096;                 \
        _Pragma("unroll 4")                                     \
        for (int k = 0; k < 32; ++k) {                          \
            float av = ar[(K0) + k];                            \
            const float4 wA = *(const float4*)(wb + k * WPAD + jA); \
            const float4 wB = *(const float4*)(wb + k * WPAD + jB); \
            aA[0] += av * wA.x; aA[1] += av * wA.y;             \
            aA[2] += av * wA.z; aA[3] += av * wA.w;             \
            aB[0] += av * wB.x; aB[1] += av * wB.y;             \
            aB[2] += av * wB.z; aB[3] += av * wB.w;             \
        }                                                       \
    }

    STORE_CHUNK(0, rvA);  LOAD_CHUNK(rvB, 32);
    __syncthreads();
    COMPUTE_CHUNK(0, 0);
    STORE_CHUNK(1, rvB);  LOAD_CHUNK(rvA, 64);
    __syncthreads();
    COMPUTE_CHUNK(1, 32);
    STORE_CHUNK(0, rvA);  LOAD_CHUNK(rvB, 96);
    __syncthreads();
    COMPUTE_CHUNK(0, 64);
    STORE_CHUNK(1, rvB);
    __syncthreads();
    COMPUTE_CHUNK(1, 96);

    // h2 = elu(acc+b2) in-register; fold out = h2@W3 (w3buf rows pad 0)
    {
        float pc[NCLS] = {0.f, 0.f, 0.f, 0.f, 0.f, 0.f};
#pragma unroll
        for (int jj = 0; jj < 4; ++jj) {
            int ja = jA + jj;
            float vA = aA[jj] + b2[ja];
            float hA = vA > 0.f ? vA : expm1f(vA);
            const float* w3a = w3buf + ja * NCLS;
#pragma unroll
            for (int cc = 0; cc < NCLS; ++cc) pc[cc] += hA * w3a[cc];
            int jb = jB + jj;
            float vB = aB[jj] + b2[jb < WIDTH ? jb : WIDTH - 1];
            float hB = (jb < WIDTH) ? (vB > 0.f ? vB : expm1f(vB)) : 0.f;
            const float* w3b = w3buf + jb * NCLS;
#pragma unroll
            for (int cc = 0; cc < NCLS; ++cc) pc[cc] += hB * w3b[cc];
        }
        // reduce across the 16 lanes of this row
#pragma unroll
        for (int mm = 1; mm < 16; mm <<= 1) {
#pragma unroll
            for (int cc = 0; cc < NCLS; ++cc)
                pc[cc] += __shfl_xor(pc[cc], mm, 16);
        }
        if (c == 0) {
#pragma unroll
            for (int cc = 0; cc < NCLS; ++cc)
                out[(size_t)gi * NCLS + cc] = pc[cc] + b3[cc];
        }
    }
#undef STORE_CHUNK
#undef LOAD_CHUNK
#undef COMPUTE_CHUNK
}

extern "C" void kernel_launch(void* const* d_in, const int* in_sizes, int n_in,
                              void* d_out, int out_size, void* d_ws, size_t ws_size,
                              hipStream_t stream) {
    const float* x     = (const float*)d_in[0];
    const int*   batch = (const int*)d_in[1];
    // Only conv index NCONV-1 == 1 affects the output (loop discards earlier)
    const float* Ws  = (const float*)d_in[2] + IN_F * SDIM;
    const float* bs  = (const float*)d_in[3] + SDIM;
    const float* Wh  = (const float*)d_in[4] + IN_F * PDIM;
    const float* bh  = (const float*)d_in[5] + PDIM;
    const float* Wo1 = (const float*)d_in[6] + IN_F * IN_F;
    const float* Wo2 = (const float*)d_in[7] + 2 * PDIM * IN_F;
    const float* bo2 = (const float*)d_in[8] + IN_F;
    const float* W1  = (const float*)d_in[9];
    const float* b1  = (const float*)d_in[10];
    const float* W2  = (const float*)d_in[11];
    const float* b2  = (const float*)d_in[12];
    const float* W3  = (const float*)d_in[13];
    const float* b3  = (const float*)d_in[14];
    float* out = (float*)d_out;

    char* ws = (char*)d_ws;
    int*   ranges = (int*)(ws + OFF_RANGES);
    float* S      = (float*)(ws + OFF_S);
    float* H      = (float*)(ws + OFF_H);
    int*   KIDX   = (int*)(ws + OFF_KIDX);
    float* KW     = (float*)(ws + OFF_KW);

    k_sh<<<dim3(NPT * 32 / 256), dim3(256), 0, stream>>>(x, batch, Ws, bs, Wh, bh, S, H, ranges);
    k_knn<<<dim3(NPT / 8), dim3(256), 0, stream>>>((const float4*)S, batch, ranges, KIDX, KW);
    k_fused<<<dim3(NPT / ROWS), dim3(512), 0, stream>>>(x, H, KIDX, KW, Wo1, Wo2, bo2,
                                                        W1, b1, W2, b2, W3, b3, out);
}

// Round 14
// 76.436 us; speedup vs baseline: 1.7995x; 1.2167x over previous
//
#include <hip/hip_runtime.h>
#include <math.h>
#include <float.h>

// Problem constants (from reference)
#define NPT     16384
#define IN_F    34
#define SDIM    4
#define PDIM    22
#define KNN     8
#define WIDTH   126
#define WPAD    128    // padded width for conflict-free LDS
#define NCLS    6
#define ROWS    32     // rows per fused-MLP block (512 threads, 16 lanes/row)

typedef unsigned long long u64;

// ---------------- workspace layout (bytes), total ~3 MB ----------------
#define OFF_RANGES 0
#define OFF_S      256
#define OFF_H      (OFF_S  + NPT*SDIM*4)
#define OFF_KIDX   (OFF_H  + NPT*PDIM*4)
#define OFF_KW     (OFF_KIDX + NPT*KNN*4)

// key bits = (float_bits(d2) << 32) | j : u64 order == lex (d2, idx) order ==
// jax.lax.top_k tie-breaking. d2 >= 0 -> high word <= 0x7f7fffff -> as an f64
// the key is POSITIVE and never NaN/Inf (exponent field < 0x7FF), so IEEE f64
// ordering == unsigned bit ordering. That lets the whole network run on
// v_min_f64/v_max_f64: CE = 2 instr (vs 5 for u64), min = 1 (vs 3).
#define INITK_BITS 0x7f7fffffffffffffULL

__device__ __forceinline__ void ce(double& a, double& b) {   // a=min, b=max
    double mn = __builtin_fmin(a, b);
    double mx = __builtin_fmax(a, b);
    a = mn; b = mx;
}
__device__ __forceinline__ double dmin64(double a, double b) {
    return __builtin_fmin(a, b);
}
__device__ __forceinline__ double pack_key(float d2, unsigned j) {
    return __longlong_as_double((long long)(((u64)__float_as_uint(d2) << 32) | j));
}

// branchless insert of one key into a sorted-8 list (used only on the tail)
__device__ __forceinline__ void key_insert(double key, double* u) {
#pragma unroll
    for (int t = 0; t < KNN; ++t) {
        double mn = __builtin_fmin(key, u[t]);
        double mx = __builtin_fmax(key, u[t]);
        u[t] = mn;
        key  = mx;
    }
}

// match reference numerics: rounded squares, sequential sum, no fma
__device__ __forceinline__ float dist2(const float4 a, const float4 b) {
    float d0 = a.x - b.x;
    float d1 = a.y - b.y;
    float d2 = a.z - b.z;
    float d3 = a.w - b.w;
    return __fadd_rn(__fadd_rn(__fadd_rn(__fmul_rn(d0, d0),
                                         __fmul_rn(d1, d1)),
                               __fmul_rn(d2, d2)),
                     __fmul_rn(d3, d3));
}

// 12-CE bitonic sort of a bitonic 8-sequence (m0..m7), ascending result
#define BITONIC8(m0,m1,m2,m3,m4,m5,m6,m7) \
    ce(m0,m4); ce(m1,m5); ce(m2,m6); ce(m3,m7); \
    ce(m0,m2); ce(m1,m3); ce(m4,m6); ce(m5,m7); \
    ce(m0,m1); ce(m2,m3); ce(m4,m5); ce(m6,m7);

// Batcher odd-even mergesort network for 8 keys (19 CE), ascending
#define SORT8(k0,k1,k2,k3,k4,k5,k6,k7) \
    ce(k0,k1); ce(k2,k3); ce(k4,k5); ce(k6,k7); \
    ce(k0,k2); ce(k1,k3); ce(k4,k6); ce(k5,k7); \
    ce(k1,k2); ce(k5,k6); \
    ce(k0,k4); ce(k1,k5); ce(k2,k6); ce(k3,k7); \
    ce(k2,k4); ce(k3,k5); \
    ce(k1,k2); ce(k3,k4); ce(k5,k6);

// ---------------------------------------------------------
// s = (x@Ws + bs) + 1000*batch ; h = x@Wh + bh  (conv index 1 weights).
// Thread = (row i, slot o): o<4 -> S, o<26 -> H, o==31 -> graph ranges.
__global__ __launch_bounds__(256) void k_sh(const float* __restrict__ x,
                                            const int* __restrict__ batch,
                                            const float* __restrict__ Ws,
                                            const float* __restrict__ bs,
                                            const float* __restrict__ Wh,
                                            const float* __restrict__ bh,
                                            float* __restrict__ S,
                                            float* __restrict__ H,
                                            int* __restrict__ ranges) {
    int t = blockIdx.x * blockDim.x + threadIdx.x;
    int i = t >> 5;
    int o = t & 31;
    if (i >= NPT) return;
    if (o == 31) {  // graph ranges from sorted batch
        int b = batch[i];
        if (i == 0 || batch[i - 1] != b) ranges[b * 2]     = i;
        if (i == NPT - 1 || batch[i + 1] != b) ranges[b * 2 + 1] = i + 1;
        return;
    }
    const float* xr = x + (size_t)i * IN_F;
    if (o < SDIM) {
        float acc = 0.f;
        for (int k = 0; k < IN_F; ++k) acc += xr[k] * Ws[k * SDIM + o];
        S[(size_t)i * SDIM + o] = (acc + bs[o]) + 1000.f * (float)batch[i];
    } else if (o < SDIM + PDIM) {
        int p = o - SDIM;
        float acc = 0.f;
        for (int k = 0; k < IN_F; ++k) acc += xr[k] * Wh[k * PDIM + p];
        H[(size_t)i * PDIM + p] = acc + bh[p];
    }
}

// Fused kNN: 32 lanes per query, interleaved candidates, batch-8 Batcher
// sort + keep-low-8 bitonic merge, butterfly across lanes -- round 13
// structure with round-14's f64 min/max networks (exact same key order).
__global__ __launch_bounds__(256, 4) void k_knn(const float4* __restrict__ S4,
                                                const int* __restrict__ batch,
                                                const int* __restrict__ ranges,
                                                int* __restrict__ KIDX,
                                                float* __restrict__ KW) {
    const int tid = threadIdx.x;
    const int q   = blockIdx.x * 8 + (tid >> 5);
    const int t   = tid & 31;
    const int b   = batch[q];
    const int gs  = ranges[b * 2];
    const int len = ranges[b * 2 + 1] - gs;
    const float4 sq = S4[q];

    double u[KNN];
    const double initk = __longlong_as_double((long long)INITK_BITS);
#pragma unroll
    for (int e = 0; e < KNN; ++e) u[e] = initk;

    int j = gs + t;
    int done = 0;

    // full 256-candidate (8/lane) batches
    const int nfull8 = len >> 8;
    for (int bb = 0; bb < nfull8; ++bb, j += 256) {
        const float4* p = S4 + j;
        float4 s0 = p[0];
        float4 s1 = p[32];
        float4 s2 = p[64];
        float4 s3 = p[96];
        float4 s4 = p[128];
        float4 s5 = p[160];
        float4 s6 = p[192];
        float4 s7 = p[224];
        double k0 = pack_key(dist2(sq, s0), (unsigned)(j));
        double k1 = pack_key(dist2(sq, s1), (unsigned)(j + 32));
        double k2 = pack_key(dist2(sq, s2), (unsigned)(j + 64));
        double k3 = pack_key(dist2(sq, s3), (unsigned)(j + 96));
        double k4 = pack_key(dist2(sq, s4), (unsigned)(j + 128));
        double k5 = pack_key(dist2(sq, s5), (unsigned)(j + 160));
        double k6 = pack_key(dist2(sq, s6), (unsigned)(j + 192));
        double k7 = pack_key(dist2(sq, s7), (unsigned)(j + 224));
        SORT8(k0, k1, k2, k3, k4, k5, k6, k7);
        // half-cleaner of (ascending k | descending u), keep-low-8 is bitonic
        double m0 = dmin64(k0, u[7]);
        double m1 = dmin64(k1, u[6]);
        double m2 = dmin64(k2, u[5]);
        double m3 = dmin64(k3, u[4]);
        double m4 = dmin64(k4, u[3]);
        double m5 = dmin64(k5, u[2]);
        double m6 = dmin64(k6, u[1]);
        double m7 = dmin64(k7, u[0]);
        BITONIC8(m0, m1, m2, m3, m4, m5, m6, m7);
        u[0] = m0; u[1] = m1; u[2] = m2; u[3] = m3;
        u[4] = m4; u[5] = m5; u[6] = m6; u[7] = m7;
    }
    done = nfull8 << 8;

    // at most one 128-candidate (4/lane) batch
    if (len - done >= 128) {
        const float4* p = S4 + j;
        float4 s0 = p[0];
        float4 s1 = p[32];
        float4 s2 = p[64];
        float4 s3 = p[96];
        double k0 = pack_key(dist2(sq, s0), (unsigned)(j));
        double k1 = pack_key(dist2(sq, s1), (unsigned)(j + 32));
        double k2 = pack_key(dist2(sq, s2), (unsigned)(j + 64));
        double k3 = pack_key(dist2(sq, s3), (unsigned)(j + 96));
        ce(k0, k1); ce(k2, k3); ce(k0, k2); ce(k1, k3); ce(k1, k2);
        double m0 = dmin64(k0, u[7]);
        double m1 = dmin64(k1, u[6]);
        double m2 = dmin64(k2, u[5]);
        double m3 = dmin64(k3, u[4]);
        double m4 = u[3], m5 = u[2], m6 = u[1], m7 = u[0];
        BITONIC8(m0, m1, m2, m3, m4, m5, m6, m7);
        u[0] = m0; u[1] = m1; u[2] = m2; u[3] = m3;
        u[4] = m4; u[5] = m5; u[6] = m6; u[7] = m7;
        done += 128;
    }

    // tail: per-lane <=4 singleton inserts (exact; order irrelevant)
    for (int m = done + t; m < len; m += 32) {
        int jj = gs + m;
        key_insert(pack_key(dist2(sq, S4[jj]), (unsigned)jj), u);
    }

    // butterfly across the 32-lane group: merge two sorted-8 lists per step
#pragma unroll
    for (int mm = 1; mm < 32; mm <<= 1) {
        double p0 = __shfl_xor(u[0], mm, 32);
        double p1 = __shfl_xor(u[1], mm, 32);
        double p2 = __shfl_xor(u[2], mm, 32);
        double p3 = __shfl_xor(u[3], mm, 32);
        double p4 = __shfl_xor(u[4], mm, 32);
        double p5 = __shfl_xor(u[5], mm, 32);
        double p6 = __shfl_xor(u[6], mm, 32);
        double p7 = __shfl_xor(u[7], mm, 32);
        double m0 = dmin64(u[0], p7);
        double m1 = dmin64(u[1], p6);
        double m2 = dmin64(u[2], p5);
        double m3 = dmin64(u[3], p4);
        double m4 = dmin64(u[4], p3);
        double m5 = dmin64(u[5], p2);
        double m6 = dmin64(u[6], p1);
        double m7 = dmin64(u[7], p0);
        BITONIC8(m0, m1, m2, m3, m4, m5, m6, m7);
        u[0] = m0; u[1] = m1; u[2] = m2; u[3] = m3;
        u[4] = m4; u[5] = m5; u[6] = m6; u[7] = m7;
    }

    if (t == 0) {
#pragma unroll
        for (int e = 0; e < KNN; ++e) {
            u64 bits = (u64)__double_as_longlong(u[e]);
            float d = __uint_as_float((unsigned)(bits >> 32));
            KIDX[(size_t)q * KNN + e] = (int)(unsigned)(bits & 0xffffffffu);
            KW[(size_t)q * KNN + e]   = expf(-10.f * d);
        }
    }
}

// Fused gather+MLP (round-11 version, verbatim -- 97.6us baseline):
//  - ROWS=32 @ 512 threads -> grid 512 = exactly 2 resident blocks/CU.
//  - W2 double-buffered + register-staged: chunk k+1's loads issued before
//    chunk k's compute; ONE barrier per chunk.
//  - chunk0 loads issued before the et phase.
//  - h2 -> out folded in-register (width-16 shfl reduce).
__global__ __launch_bounds__(512, 4) void k_fused(
        const float* __restrict__ x,
        const float* __restrict__ H,
        const int* __restrict__ KIDX,
        const float* __restrict__ KW,
        const float* __restrict__ Wo1,
        const float* __restrict__ Wo2,
        const float* __restrict__ bo2,
        const float* __restrict__ W1,
        const float* __restrict__ b1,
        const float* __restrict__ W2,
        const float* __restrict__ b2,
        const float* __restrict__ W3,
        const float* __restrict__ b3,
        float* __restrict__ out) {
    __shared__ float xt[ROWS * IN_F];       // 32x34
    __shared__ float aggt[ROWS * 2 * PDIM]; // 32x44
    __shared__ float et[ROWS * IN_F];       // 32x34
    __shared__ float h1t[ROWS * WPAD];      // 32x128 (cols 126/127 = 0)
    __shared__ float wbuf[2 * 32 * WPAD];   // 2 x 32x128: W1 (34 rows split
                                            // [0]=rows0-31,[1]=rows32-33), then
                                            // W2 double-buffer. 32 KB.
    __shared__ float w3buf[WPAD * NCLS];    // 128x6, rows 126/127 = 0
                                            // total = 66560 B -> 2 blocks/CU

    const int tid  = threadIdx.x;
    const int r    = tid >> 4;              // row 0..31
    const int c    = tid & 15;              // lane-in-row 0..15
    const int row0 = blockIdx.x * ROWS;
    const int gi   = row0 + r;
    const int jA   = 4 * c;                 // cols 0..63
    const int jB   = 64 + 4 * c;            // cols 64..127 (126/127 pad)

    // ---- staging: x, W1 (rows split over both wbuf halves), W3 ----
    for (int t = tid; t < ROWS * IN_F; t += 512)
        xt[t] = x[(size_t)row0 * IN_F + t];
    for (int t = tid; t < IN_F * WPAD; t += 512) {
        int k = t >> 7, j = t & 127;
        wbuf[(k >> 5) * (32 * WPAD) + (k & 31) * WPAD + j] =
            (j < WIDTH) ? W1[k * WIDTH + j] : 0.f;
    }
    for (int t = tid; t < WPAD * NCLS; t += 512) {
        int k = t / NCLS;
        w3buf[t] = (k < WIDTH) ? W3[t] : 0.f;
    }

    // gather + aggregate: lane c<11 handles dims {c, c+11}
    if (c < 11) {
        const int p0 = c, p1 = c + 11;
        float s0 = 0.f, s1 = 0.f;
        float m0 = -FLT_MAX, m1 = -FLT_MAX;
#pragma unroll
        for (int k = 0; k < KNN; ++k) {
            int   j = KIDX[(size_t)gi * KNN + k];
            float w = KW[(size_t)gi * KNN + k];
            const float* hr = H + (size_t)j * PDIM;
            float v0 = hr[p0] * w; s0 += v0; m0 = fmaxf(m0, v0);
            float v1 = hr[p1] * w; s1 += v1; m1 = fmaxf(m1, v1);
        }
        aggt[r * 44 + p0] = s0 * 0.125f; aggt[r * 44 + PDIM + p0] = m0;
        aggt[r * 44 + p1] = s1 * 0.125f; aggt[r * 44 + PDIM + p1] = m1;
    }
    __syncthreads();   // xt, W1, w3, aggt all visible

    // issue W2 chunk0 loads NOW; they drain under et + h1 compute.
    float rvA[8], rvB[8];
#pragma unroll
    for (int i = 0; i < 8; ++i) {
        int e = i * 512 + tid, kk = e >> 7, j = e & 127;
        rvA[i] = (j < WIDTH) ? W2[(size_t)kk * WIDTH + j] : 0.f;  // rows 0..31
    }

    // et = x@Wo1 + agg@Wo2 + bo2 ; 3-wide chunks, j0=min(3c,31); overlap
    // lanes write bitwise-identical duplicates (benign); Wo1/Wo2 L1/L2-hot
    {
        const int j0 = (3 * c < 31) ? 3 * c : 31;
        float acc[3] = {0.f, 0.f, 0.f};
        const float* ar = xt + r * IN_F;
#pragma unroll 4
        for (int k = 0; k < IN_F; ++k) {
            float av = ar[k];
            const float* wr = Wo1 + k * IN_F + j0;
#pragma unroll
            for (int jj = 0; jj < 3; ++jj) acc[jj] += av * wr[jj];
        }
        const float* gr = aggt + r * 44;
#pragma unroll 4
        for (int p = 0; p < 2 * PDIM; ++p) {
            float av = gr[p];
            const float* wr = Wo2 + p * IN_F + j0;
#pragma unroll
            for (int jj = 0; jj < 3; ++jj) acc[jj] += av * wr[jj];
        }
#pragma unroll
        for (int jj = 0; jj < 3; ++jj)
            et[r * IN_F + j0 + jj] = acc[jj] + bo2[j0 + jj];
    }
    __syncthreads();   // et ready

    // h1 = elu(et@W1 + b1), W1 from LDS (rows k: half k>>5, row k&31)
    {
        float aA[4] = {0.f, 0.f, 0.f, 0.f};
        float aB[4] = {0.f, 0.f, 0.f, 0.f};
        const float* ar = et + r * IN_F;
#pragma unroll 4
        for (int k = 0; k < IN_F; ++k) {
            float av = ar[k];
            const float* wr = wbuf + (k >> 5) * (32 * WPAD) + (k & 31) * WPAD;
            const float4 wA = *(const float4*)(wr + jA);
            const float4 wB = *(const float4*)(wr + jB);
            aA[0] += av * wA.x; aA[1] += av * wA.y;
            aA[2] += av * wA.z; aA[3] += av * wA.w;
            aB[0] += av * wB.x; aB[1] += av * wB.y;
            aB[2] += av * wB.z; aB[3] += av * wB.w;
        }
#pragma unroll
        for (int jj = 0; jj < 4; ++jj) {
            float vA = aA[jj] + b1[jA + jj];
            h1t[r * WPAD + jA + jj] = vA > 0.f ? vA : expm1f(vA);
            int j = jB + jj;
            float vB = aB[jj] + b1[j < WIDTH ? j : WIDTH - 1];
            h1t[r * WPAD + j] = (j < WIDTH) ? (vB > 0.f ? vB : expm1f(vB)) : 0.f;
        }
    }
    __syncthreads();   // h1t ready; ALL W1 reads done -> wbuf reusable

    // ---- h2 with double-buffered W2 (one barrier per chunk) ----
    float aA[4] = {0.f, 0.f, 0.f, 0.f};
    float aB[4] = {0.f, 0.f, 0.f, 0.f};
    const float* ar = h1t + r * WPAD;

#define STORE_CHUNK(BUFI, RV)                                   \
    _Pragma("unroll")                                           \
    for (int i = 0; i < 8; ++i)                                 \
        wbuf[(BUFI) * 4096 + i * 512 + tid] = RV[i];

#define LOAD_CHUNK(RV, K0)                                      \
    _Pragma("unroll")                                           \
    for (int i = 0; i < 8; ++i) {                               \
        int e = i * 512 + tid, kk = e >> 7, j = e & 127;        \
        int row = (K0) + kk;                                    \
        RV[i] = (j < WIDTH && row < WIDTH)                      \
                    ? W2[(size_t)row * WIDTH + j] : 0.f;        \
    }

#define COMPUTE_CHUNK(BUFI, K0)                                 \
    {                                                           \
        const float* wb = wbuf + (BUFI) * 4096;                 \
        _Pragma("unroll 4")                                     \
        for (int k = 0; k < 32; ++k) {                          \
            float av = ar[(K0) + k];                            \
            const float4 wA = *(const float4*)(wb + k * WPAD + jA); \
            const float4 wB = *(const float4*)(wb + k * WPAD + jB); \
            aA[0] += av * wA.x; aA[1] += av * wA.y;             \
            aA[2] += av * wA.z; aA[3] += av * wA.w;             \
            aB[0] += av * wB.x; aB[1] += av * wB.y;             \
            aB[2] += av * wB.z; aB[3] += av * wB.w;             \
        }                                                       \
    }

    STORE_CHUNK(0, rvA);  LOAD_CHUNK(rvB, 32);
    __syncthreads();
    COMPUTE_CHUNK(0, 0);
    STORE_CHUNK(1, rvB);  LOAD_CHUNK(rvA, 64);
    __syncthreads();
    COMPUTE_CHUNK(1, 32);
    STORE_CHUNK(0, rvA);  LOAD_CHUNK(rvB, 96);
    __syncthreads();
    COMPUTE_CHUNK(0, 64);
    STORE_CHUNK(1, rvB);
    __syncthreads();
    COMPUTE_CHUNK(1, 96);

    // h2 = elu(acc+b2) in-register; fold out = h2@W3 (w3buf rows pad 0)
    {
        float pc[NCLS] = {0.f, 0.f, 0.f, 0.f, 0.f, 0.f};
#pragma unroll
        for (int jj = 0; jj < 4; ++jj) {
            int ja = jA + jj;
            float vA = aA[jj] + b2[ja];
            float hA = vA > 0.f ? vA : expm1f(vA);
            const float* w3a = w3buf + ja * NCLS;
#pragma unroll
            for (int cc = 0; cc < NCLS; ++cc) pc[cc] += hA * w3a[cc];
            int jb = jB + jj;
            float vB = aB[jj] + b2[jb < WIDTH ? jb : WIDTH - 1];
            float hB = (jb < WIDTH) ? (vB > 0.f ? vB : expm1f(vB)) : 0.f;
            const float* w3b = w3buf + jb * NCLS;
#pragma unroll
            for (int cc = 0; cc < NCLS; ++cc) pc[cc] += hB * w3b[cc];
        }
        // reduce across the 16 lanes of this row
#pragma unroll
        for (int mm = 1; mm < 16; mm <<= 1) {
#pragma unroll
            for (int cc = 0; cc < NCLS; ++cc)
                pc[cc] += __shfl_xor(pc[cc], mm, 16);
        }
        if (c == 0) {
#pragma unroll
            for (int cc = 0; cc < NCLS; ++cc)
                out[(size_t)gi * NCLS + cc] = pc[cc] + b3[cc];
        }
    }
#undef STORE_CHUNK
#undef LOAD_CHUNK
#undef COMPUTE_CHUNK
}

extern "C" void kernel_launch(void* const* d_in, const int* in_sizes, int n_in,
                              void* d_out, int out_size, void* d_ws, size_t ws_size,
                              hipStream_t stream) {
    const float* x     = (const float*)d_in[0];
    const int*   batch = (const int*)d_in[1];
    // Only conv index NCONV-1 == 1 affects the output (loop discards earlier)
    const float* Ws  = (const float*)d_in[2] + IN_F * SDIM;
    const float* bs  = (const float*)d_in[3] + SDIM;
    const float* Wh  = (const float*)d_in[4] + IN_F * PDIM;
    const float* bh  = (const float*)d_in[5] + PDIM;
    const float* Wo1 = (const float*)d_in[6] + IN_F * IN_F;
    const float* Wo2 = (const float*)d_in[7] + 2 * PDIM * IN_F;
    const float* bo2 = (const float*)d_in[8] + IN_F;
    const float* W1  = (const float*)d_in[9];
    const float* b1  = (const float*)d_in[10];
    const float* W2  = (const float*)d_in[11];
    const float* b2  = (const float*)d_in[12];
    const float* W3  = (const float*)d_in[13];
    const float* b3  = (const float*)d_in[14];
    float* out = (float*)d_out;

    char* ws = (char*)d_ws;
    int*   ranges = (int*)(ws + OFF_RANGES);
    float* S      = (float*)(ws + OFF_S);
    float* H      = (float*)(ws + OFF_H);
    int*   KIDX   = (int*)(ws + OFF_KIDX);
    float* KW     = (float*)(ws + OFF_KW);

    k_sh<<<dim3(NPT * 32 / 256), dim3(256), 0, stream>>>(x, batch, Ws, bs, Wh, bh, S, H, ranges);
    k_knn<<<dim3(NPT / 8), dim3(256), 0, stream>>>((const float4*)S, batch, ranges, KIDX, KW);
    k_fused<<<dim3(NPT / ROWS), dim3(512), 0, stream>>>(x, H, KIDX, KW, Wo1, Wo2, bo2,
                                                        W1, b1, W2, b2, W3, b3, out);
}